// Round 10
// baseline (1271.082 us; speedup 1.0000x reference)
//
#include <hip/hip_runtime.h>

// DegModel: kernel-prediction net (17x conv3x3 + 1x1 conv to 441 taps) +
// tap-normalized spatially-varying 21x21 downsample (stride 4, reflect pad).
//
// fp64 conv chain (1/tap-sum amplification: fp32 chain fails 1280 > 1177;
// fp64 passes at 576). Round 10:
//  - conv3x3: fp64 MFMA GEMM (r9, probed fragment layouts) + DEPTH-2
//    register prefetch (slots are phase-aligned: step s -> slot s%3), giving
//    B-loads a ~128cyc/wave lead over consumption. K-order unchanged ->
//    bit-identical conv outputs.
//  - lastconv: rewritten as fp64 MFMA GEMM D(64pos x 448taps) = H * WtF
//    using the same probed tables (r9 version was r4-era vector FMA: 87 us
//    at VALUBusy 33%). Tap-sums via separate exact-refactored kernel:
//    sums = sum_c h*(sum_T W) + sum_T b (fp64 reassoc ~1e-15 rel, harmless).
// On-device layout probe (r8 lesson: assumed f64 MFMA maps were wrong).

#define NB 8        // batch
#define NF 64       // features
#define SP 4096     // 64*64 spatial
#define PS 66       // padded spatial dim
#define PS2 4356    // 66*66
#define K2 441      // 21*21 taps
#define K2P 448     // padded taps
#define RES_WSTRIDE (64*64*9)
#define WF_RES 49152           // per-layer fragment weights: 64c*3ph*4mt*64
#define WF_C0  2304            // 3c*3ph*4mt*64
#define WTF_N  28672           // 16kk * 28nt * 64

typedef double vdbl4 __attribute__((ext_vector_type(4)));

// table offsets (ints) within the tabs block
#define T_AI 0      // [64]  A: lane -> i
#define T_AK 64     // [64]  A: lane -> k
#define T_BK 128    // [64]  B: lane -> k
#define T_BJ 192    // [64]  B: lane -> j
#define T_DI 256    // [256] D: r*64+l -> i
#define T_DJ 512    // [256] D: r*64+l -> j

// ---------------------------------------------------------------------------
// layout probe: one wave. D1[l,r] = rowsumA(i(l,r)), D2[l,r] = colsumB(j(l,r))
__global__ void probe_mfma(double* __restrict__ probe)
{
    int l = threadIdx.x;
    vdbl4 z = {0.0, 0.0, 0.0, 0.0};
    vdbl4 r1 = __builtin_amdgcn_mfma_f64_16x16x4f64((double)l, 1.0, z, 0, 0, 0);
    vdbl4 r2 = __builtin_amdgcn_mfma_f64_16x16x4f64(1.0, (double)l, z, 0, 0, 0);
#pragma unroll
    for (int r = 0; r < 4; ++r) {
        probe[r * 64 + l]       = r1[r];
        probe[256 + r * 64 + l] = r2[r];
    }
}

__global__ void decode_probe(const double* __restrict__ probe, int* __restrict__ tabs)
{
    int t = threadIdx.x;                 // 0..255
    const double* d1 = probe;
    const double* d2 = probe + 256;
    // lane=i+16k => rowsum=96+4i (mod4==0); lane=4i+k => 6+16i (mod4==2)
    bool fA = ((((int)d1[0]) & 3) == 0);
    bool fB = ((((int)d2[0]) & 3) == 0);
    int v1 = (int)d1[t], v2 = (int)d2[t];
    tabs[T_DI + t] = fA ? (v1 - 96) >> 2 : (v1 - 6) >> 4;
    tabs[T_DJ + t] = fB ? (v2 - 96) >> 2 : (v2 - 6) >> 4;
    if (t < 64) {
        tabs[T_AI + t] = fA ? (t & 15) : (t >> 2);
        tabs[T_AK + t] = fA ? (t >> 4) : (t & 3);
        tabs[T_BK + t] = fB ? (t >> 4) : (t & 3);
        tabs[T_BJ + t] = fB ? (t & 15) : (t >> 2);
    }
}

// ---------------------------------------------------------------------------
// z (8,3,64,64) fp32 -> zp (8,3,66,66) fp64 interior (borders pre-zeroed)
__global__ void prep_zpad(const float* __restrict__ z, double* __restrict__ zp)
{
    int i = blockIdx.x * blockDim.x + threadIdx.x;
    if (i >= NB * 3 * SP) return;
    int bc = i >> 12, p = i & 4095, y = p >> 6, x = p & 63;
    zp[(size_t)(bc * PS + y + 1) * PS + x + 1] = (double)z[i];
}

// conv weights OIHW fp32 -> MFMA A-fragment order (table-driven), fp64
__global__ void prep_convw_frag(const float* __restrict__ src, double* __restrict__ dst,
                                const int* __restrict__ tabs,
                                int CIN, int nlayer, int wstride)
{
    int i = blockIdx.x * blockDim.x + threadIdx.x;
    int M = CIN * 768;                   // CIN*3*4*64 per layer
    if (i >= nlayer * M) return;
    int li  = i / M;
    int rem = i - li * M;
    int t4  = rem >> 8;
    int j   = rem & 255;
    int mt  = j >> 6;
    int l   = j & 63;
    int c   = t4 / 3;
    int ph  = t4 - c * 3;
    int oc  = mt * 16 + tabs[T_AI + l];
    int tap = ph * 4 + tabs[T_AK + l];
    dst[i] = (tap < 9) ? (double)src[li * wstride + (oc * CIN + c) * 9 + tap] : 0.0;
}

// bias fp32 -> C-fragment order fp64
__global__ void prep_bias_frag(const float* __restrict__ src, double* __restrict__ dst,
                               const int* __restrict__ tabs, int nlayer)
{
    int i = blockIdx.x * blockDim.x + threadIdx.x;
    if (i >= nlayer * 1024) return;
    int li  = i >> 10;
    int j   = i & 1023;
    int mtr = j >> 6;
    int l   = j & 63;
    int mt  = mtr >> 2, r = mtr & 3;
    dst[i] = (double)src[li * 64 + mt * 16 + tabs[T_DI + r * 64 + l]];
}

// last_w (441,64) -> B-fragment order WtF[kk][nt][lane] =
// W[tap = nt*16+Bj(l)][c = kk*4+Bk(l)] (tap>=441 -> 0); lbp padded bias.
__global__ void prep_lastwf(const float* __restrict__ lw, const float* __restrict__ lb,
                            const int* __restrict__ tabs,
                            double* __restrict__ wtf, double* __restrict__ lbp)
{
    int i = blockIdx.x * blockDim.x + threadIdx.x;
    if (i < WTF_N) {
        int kk = i / (28 * 64);
        int rem = i - kk * (28 * 64);
        int nt = rem >> 6;
        int l  = rem & 63;
        int c  = kk * 4 + tabs[T_BK + l];
        int T  = nt * 16 + tabs[T_BJ + l];
        wtf[i] = (T < K2) ? (double)lw[T * 64 + c] : 0.0;
    }
    if (i < K2P) lbp[i] = (i < K2) ? (double)lb[i] : 0.0;
}

// wsum[c] = sum_T lw[T][c] (fp64, T-ascending); wsum[64] = sum_T lb[T]
__global__ void prep_wsum(const float* __restrict__ lw, const float* __restrict__ lb,
                          double* __restrict__ wsum)
{
    int c = threadIdx.x;
    if (c < 64) {
        double s = 0.0;
        for (int t = 0; t < K2; ++t) s += (double)lw[t * 64 + c];
        wsum[c] = s;
    }
    if (c == 64) {
        double s = 0.0;
        for (int t = 0; t < K2; ++t) s += (double)lb[t];
        wsum[64] = s;
    }
}

// ---------------------------------------------------------------------------
// conv3x3 as fp64 MFMA GEMM: D(64oc x 64pos) = WF(64 x CIN*12) * P + bias.
// Depth-2 register prefetch: slot = step%3 (phase-aligned). Grid 512, 2/CU.
// ---------------------------------------------------------------------------
template<int CIN, bool RELU, bool RESADD>
__global__ __launch_bounds__(256, 2)
void conv3x3_mfma(const double* __restrict__ in, const double* __restrict__ WF,
                  const double* __restrict__ BF, const int* __restrict__ tabs,
                  const double* __restrict__ res, double* __restrict__ out)
{
    const int bid = blockIdx.x;
    const int b   = bid & 7;
    const int y0  = bid >> 3;          // output row 0..63
    const int tid = threadIdx.x;
    const int w   = tid >> 6;
    const int l   = tid & 63;
    const int mi  = w >> 1, ni = w & 1;
    const int mt0 = mi * 2, nt0 = ni * 2;

    const int kB = tabs[T_BK + l];
    const int jB = tabs[T_BJ + l];

    // per-lane P offsets for the 3 tap-phases (pad taps alias tap 8)
    int offp[3];
#pragma unroll
    for (int ph = 0; ph < 3; ++ph) {
        int tap = ph * 4 + kB;
        if (tap > 8) tap = 8;          // weight is 0 there; just needs a valid addr
        int dy = tap / 3, dx = tap - dy * 3;
        offp[ph] = dy * PS + dx + jB;
    }

    const double* bbase = in + (size_t)b * CIN * PS2 + (size_t)y0 * PS;

    vdbl4 acc[2][2];
#pragma unroll
    for (int mt = 0; mt < 2; ++mt)
#pragma unroll
        for (int r = 0; r < 4; ++r) {
            double bv = BF[((mt0 + mt) * 4 + r) * 64 + l];
            acc[mt][0][r] = bv;
            acc[mt][1][r] = bv;
        }

    double aS[3][2], bS[3][2];
    auto ldA = [&](int s, int slot) {
        const double* p = WF + (size_t)s * 256 + l;
        aS[slot][0] = p[mt0 * 64];
        aS[slot][1] = p[(mt0 + 1) * 64];
    };
    auto ldB = [&](int c, int ph, int slot) {
        const double* p = bbase + (size_t)c * PS2 + offp[ph] + nt0 * 16;
        bS[slot][0] = p[0];
        bS[slot][1] = p[16];
    };
    auto step = [&](int slot) {
        acc[0][0] = __builtin_amdgcn_mfma_f64_16x16x4f64(aS[slot][0], bS[slot][0], acc[0][0], 0, 0, 0);
        acc[0][1] = __builtin_amdgcn_mfma_f64_16x16x4f64(aS[slot][0], bS[slot][1], acc[0][1], 0, 0, 0);
        acc[1][0] = __builtin_amdgcn_mfma_f64_16x16x4f64(aS[slot][1], bS[slot][0], acc[1][0], 0, 0, 0);
        acc[1][1] = __builtin_amdgcn_mfma_f64_16x16x4f64(aS[slot][1], bS[slot][1], acc[1][1], 0, 0, 0);
    };

    // preload steps 0 and 1
    ldA(0, 0); ldB(0, 0, 0);
    ldA(1, 1); ldB(0, 1, 1);

    for (int c = 0; c < CIN; ++c) {
        const int s = 3 * c;
        // phase 0: issue (c,2) -> slot 2, compute slot 0
        ldA(s + 2, 2); ldB(c, 2, 2);
        step(0);
        // phase 1: issue (c+1,0) -> slot 0, compute slot 1
        if (c + 1 < CIN) { ldA(s + 3, 0); ldB(c + 1, 0, 0); }
        step(1);
        // phase 2: issue (c+1,1) -> slot 1, compute slot 2
        if (c + 1 < CIN) { ldA(s + 4, 1); ldB(c + 1, 1, 1); }
        step(2);
    }

    // epilogue: D element (i,j) per (lane, reg) from probe tables
    int iD[4], jD[4];
#pragma unroll
    for (int r = 0; r < 4; ++r) {
        iD[r] = tabs[T_DI + r * 64 + l];
        jD[r] = tabs[T_DJ + r * 64 + l];
    }
#pragma unroll
    for (int mt = 0; mt < 2; ++mt)
#pragma unroll
        for (int nt = 0; nt < 2; ++nt)
#pragma unroll
            for (int r = 0; r < 4; ++r) {
                int oc = (mt0 + mt) * 16 + iD[r];
                int x  = (nt0 + nt) * 16 + jD[r];
                size_t idx = (size_t)(b * NF + oc) * PS2 + (size_t)(y0 + 1) * PS + x + 1;
                double val = acc[mt][nt][r];
                if (RELU)   val = fmax(val, 0.0);
                if (RESADD) val += res[idx];
                out[idx] = val;
            }
}

// ---------------------------------------------------------------------------
// 1x1 conv as fp64 MFMA GEMM: D(64pos x 448taps) = H(64pos x 64c) * WtF.
// Block = (b,row), 4 waves; wave w owns n-tiles w*7..w*7+6; mt loop over the
// 4 pos-tiles. Raw taps stored fp32 into d_out kernel region.
// Grid: 8 b * 64 rows = 512 blocks, 2/CU. No LDS.
// ---------------------------------------------------------------------------
__global__ __launch_bounds__(256, 2)
void lastconv_mfma(const double* __restrict__ hp, const double* __restrict__ wtf,
                   const double* __restrict__ lbp, const int* __restrict__ tabs,
                   float* __restrict__ kraw)
{
    const int b   = blockIdx.x >> 6;
    const int row = blockIdx.x & 63;
    const int tid = threadIdx.x;
    const int w   = tid >> 6;
    const int l   = tid & 63;

    const int iA = tabs[T_AI + l];
    const int kA = tabs[T_AK + l];
    int iD[4], jD[4];
#pragma unroll
    for (int r = 0; r < 4; ++r) {
        iD[r] = tabs[T_DI + r * 64 + l];
        jD[r] = tabs[T_DJ + r * 64 + l];
    }

    const double* hbase = hp + (size_t)b * NF * PS2 + (size_t)(row + 1) * PS + 1;
    const int nt0 = w * 7;

    for (int mt = 0; mt < 4; ++mt) {
        vdbl4 acc[7];
#pragma unroll
        for (int n = 0; n < 7; ++n)
#pragma unroll
            for (int r = 0; r < 4; ++r)
                acc[n][r] = lbp[(nt0 + n) * 16 + jD[r]];

        // prefetch A for kk=0
        double a = hbase[(size_t)kA * PS2 + mt * 16 + iA];
        for (int kk = 0; kk < 16; ++kk) {
            double na = 0.0;
            if (kk < 15)
                na = hbase[(size_t)((kk + 1) * 4 + kA) * PS2 + mt * 16 + iA];
            const double* bp_ = wtf + ((size_t)kk * 28 + nt0) * 64 + l;
#pragma unroll
            for (int n = 0; n < 7; ++n)
                acc[n] = __builtin_amdgcn_mfma_f64_16x16x4f64(a, bp_[n * 64], acc[n], 0, 0, 0);
            a = na;
        }

#pragma unroll
        for (int n = 0; n < 7; ++n)
#pragma unroll
            for (int r = 0; r < 4; ++r) {
                int T = (nt0 + n) * 16 + jD[r];
                if (T < K2) {
                    int pos = mt * 16 + iD[r];
                    kraw[((size_t)b * K2 + T) * SP + row * 64 + pos] = (float)acc[n][r];
                }
            }
    }
}

// ---------------------------------------------------------------------------
// sums[b][p] = sum_c hp[c,p] * wsum[c] + wsum[64]  (exact refactoring of the
// tap-sum; fp64 reassociation ~1e-15 rel, harmless vs 1/s amplification)
// ---------------------------------------------------------------------------
__global__ __launch_bounds__(256)
void sums_kernel(const double* __restrict__ hp, const double* __restrict__ wsum,
                 double* __restrict__ sums)
{
    int i = blockIdx.x * 256 + threadIdx.x;   // 0..32767
    int b = i >> 12, p = i & 4095;
    int y = p >> 6, x = p & 63;
    const double* hb = hp + (size_t)b * NF * PS2 + (size_t)(y + 1) * PS + 1 + x;
    double s = wsum[64];
    for (int c = 0; c < 64; ++c) s += hb[(size_t)c * PS2] * wsum[c];
    sums[b * SP + p] = s;
}

// ---------------------------------------------------------------------------
// Normalize kernel in place + apply to reflect-padded 21x21 patches of x.
// (unchanged — numerics here are not 1/s-amplified, fp32 ok)
// ---------------------------------------------------------------------------
__global__ __launch_bounds__(256)
void apply_kernel(const float* __restrict__ x, const double* __restrict__ sums,
                  float* __restrict__ kout, float* __restrict__ out)
{
    const int bid  = blockIdx.x;
    const int g    = bid & 3;
    const int tile = (bid >> 2) & 15;
    const int b    = bid >> 6;
    const int i0   = (tile >> 2) << 4;
    const int j0   = (tile & 3) << 4;
    const int tid  = threadIdx.x;
    const int ti   = tid >> 4, tj = tid & 15;

    __shared__ float s_x[3][81][84];

    for (int e = tid; e < 3 * 81 * 84; e += 256) {
        int c   = e / 6804;
        int rem = e - c * 6804;
        int u   = rem / 84;
        int v   = rem - u * 84;
        int gr  = i0 * 4 + u - 10;
        int gc  = j0 * 4 + v - 10;
        gr = gr < 0 ? -gr : (gr > 255 ? 510 - gr : gr);
        gc = gc < 0 ? -gc : (gc > 255 ? 510 - gc : gc);
        int vp = (v & 3) * 21 + (v >> 2);
        s_x[c][u][vp] = x[((b * 3 + c) * 256 + gr) * 256 + gc];
    }
    __syncthreads();

    const int p = (i0 + ti) * 64 + (j0 + tj);
    const double inv = 1.0 / (sums[b * SP + p] + 1e-8);

    float o0 = 0.f, o1 = 0.f, o2 = 0.f;
    const int t0 = g * 111;
    const int t1 = (t0 + 111 < K2) ? t0 + 111 : K2;
    for (int t = t0; t < t1; ++t) {
        int ty = t / 21, tx = t - ty * 21;
        float* kp = &kout[(size_t)(b * K2 + t) * SP + p];
        float k  = *kp;
        float kn = (float)((double)k * inv);
        *kp = kn;
        int u  = ti * 4 + ty;
        int vp = (tx & 3) * 21 + tj + (tx >> 2);
        o0 = fmaf(s_x[0][u][vp], kn, o0);
        o1 = fmaf(s_x[1][u][vp], kn, o1);
        o2 = fmaf(s_x[2][u][vp], kn, o2);
    }
    atomicAdd(&out[(b * 3 + 0) * SP + p], o0);
    atomicAdd(&out[(b * 3 + 1) * SP + p], o1);
    atomicAdd(&out[(b * 3 + 2) * SP + p], o2);
}

// ---------------------------------------------------------------------------
extern "C" void kernel_launch(void* const* d_in, const int* in_sizes, int n_in,
                              void* d_out, int out_size, void* d_ws, size_t ws_size,
                              hipStream_t stream)
{
    (void)in_sizes; (void)n_in; (void)out_size; (void)ws_size;

    const float* x = (const float*)d_in[0];
    const float* z = (const float*)d_in[1];

    float* out  = (float*)d_out;                 // (8,3,64,64)
    float* kout = (float*)d_out + NB * 3 * SP;   // (8,441,64,64) raw -> normalized

    // ws layout (doubles)
    double* wd    = (double*)d_ws;
    double* probe = wd;                      // 512 (D1, D2)
    int*    tabs  = (int*)(wd + 512);        // 1024 ints (=512 doubles)
    double* wf0   = wd + 1024;               // 2304
    double* wf1   = wf0 + WF_C0;             // 8*49152
    double* wf2   = wf1 + 8 * WF_RES;        // 8*49152
    double* bf0   = wf2 + 8 * WF_RES;        // 1024
    double* bf1   = bf0 + 1024;              // 8*1024
    double* bf2   = bf1 + 8 * 1024;          // 8*1024
    double* wtf   = bf2 + 8 * 1024;          // 28672
    double* lbp   = wtf + WTF_N;             // 448
    double* wsum  = lbp + K2P;               // 72
    double* zp    = wsum + 72;               // 8*3*66*66
    double* hp    = zp + NB * 3 * PS2;       // 8*64*66*66 = 17.8 MB
    double* tp    = hp + NB * NF * PS2;      // 17.8 MB
    double* sums  = tp;                      // aliases tp (free after conv chain)

    // zero padded buffers (borders must be 0; interiors get overwritten)
    hipMemsetAsync(zp, 0, (size_t)NB * 3 * PS2 * sizeof(double), stream);
    hipMemsetAsync(hp, 0, (size_t)NB * NF * PS2 * sizeof(double), stream);
    hipMemsetAsync(tp, 0, (size_t)NB * NF * PS2 * sizeof(double), stream);
    hipMemsetAsync(out, 0, NB * 3 * SP * sizeof(float), stream);

    // layout probe, then table-driven prep
    probe_mfma<<<1, 64, 0, stream>>>(probe);
    decode_probe<<<1, 256, 0, stream>>>(probe, tabs);

    prep_zpad<<<(NB * 3 * SP + 255) / 256, 256, 0, stream>>>(z, zp);
    prep_convw_frag<<<(WF_C0 + 255) / 256, 256, 0, stream>>>(
        (const float*)d_in[2], wf0, tabs, 3, 1, 0);
    prep_convw_frag<<<(8 * WF_RES + 255) / 256, 256, 0, stream>>>(
        (const float*)d_in[4], wf1, tabs, 64, 8, RES_WSTRIDE);
    prep_convw_frag<<<(8 * WF_RES + 255) / 256, 256, 0, stream>>>(
        (const float*)d_in[6], wf2, tabs, 64, 8, RES_WSTRIDE);
    prep_bias_frag<<<(1024 + 255) / 256, 256, 0, stream>>>(
        (const float*)d_in[3], bf0, tabs, 1);
    prep_bias_frag<<<(8 * 1024 + 255) / 256, 256, 0, stream>>>(
        (const float*)d_in[5], bf1, tabs, 8);
    prep_bias_frag<<<(8 * 1024 + 255) / 256, 256, 0, stream>>>(
        (const float*)d_in[7], bf2, tabs, 8);
    prep_lastwf<<<(WTF_N + 255) / 256, 256, 0, stream>>>(
        (const float*)d_in[8], (const float*)d_in[9], tabs, wtf, lbp);
    prep_wsum<<<1, 128, 0, stream>>>(
        (const float*)d_in[8], (const float*)d_in[9], wsum);

    conv3x3_mfma<3,  false, false><<<512, 256, 0, stream>>>(zp, wf0, bf0, tabs, nullptr, hp);
    for (int i = 0; i < 8; ++i) {
        conv3x3_mfma<64, true,  false><<<512, 256, 0, stream>>>(
            hp, wf1 + i * WF_RES, bf1 + i * 1024, tabs, nullptr, tp);
        conv3x3_mfma<64, false, true ><<<512, 256, 0, stream>>>(
            tp, wf2 + i * WF_RES, bf2 + i * 1024, tabs, hp, hp);
    }
    sums_kernel<<<128, 256, 0, stream>>>(hp, wsum, sums);
    lastconv_mfma<<<512, 256, 0, stream>>>(hp, wtf, lbp, tabs, kout);
    apply_kernel<<<512, 256, 0, stream>>>(x, sums, kout, out);
}

// Round 11
// 1241.198 us; speedup vs baseline: 1.0241x; 1.0241x over previous
//
#include <hip/hip_runtime.h>

// DegModel: kernel-prediction net (17x conv3x3 + 1x1 conv to 441 taps) +
// tap-normalized spatially-varying 21x21 downsample (stride 4, reflect pad).
//
// fp64 conv chain (1/tap-sum amplification: fp32 chain fails 1280 > 1177;
// fp64 passes at 576). Round 11:
//  - conv3x3: fp64 MFMA GEMM, probed fragment layouts, depth-2 register
//    prefetch (r10, kept: conv chain ~1100 us).
//  - lastconv: GEMM TRANSPOSED vs r10: D(448taps x 64pos) = Wt * H. r10's
//    (pos x taps) orientation scattered 4B stores across tap-planes ->
//    write-allocate blowup (FETCH 204 MB + WRITE 150 MB, 167 us HBM-bound).
//    Now a quad's 16 lanes share one tap row -> 64B-contiguous stores;
//    B = H coalesced; A = last_w pre-swizzled (L2-resident).
//  - tap-sums via exact refactoring: sums = sum_c h*(sum_T W) + sum_T b.
// On-device layout probe (r8 lesson: assumed f64 MFMA maps were wrong).

#define NB 8        // batch
#define NF 64       // features
#define SP 4096     // 64*64 spatial
#define PS 66       // padded spatial dim
#define PS2 4356    // 66*66
#define K2 441      // 21*21 taps
#define K2P 448     // padded taps
#define RES_WSTRIDE (64*64*9)
#define WF_RES 49152           // per-layer fragment weights: 64c*3ph*4mt*64
#define WF_C0  2304            // 3c*3ph*4mt*64
#define WTA_N  28672           // 16kk * 28mt * 64

typedef double vdbl4 __attribute__((ext_vector_type(4)));

// table offsets (ints) within the tabs block
#define T_AI 0      // [64]  A: lane -> i
#define T_AK 64     // [64]  A: lane -> k
#define T_BK 128    // [64]  B: lane -> k
#define T_BJ 192    // [64]  B: lane -> j
#define T_DI 256    // [256] D: r*64+l -> i
#define T_DJ 512    // [256] D: r*64+l -> j

// ---------------------------------------------------------------------------
// layout probe: one wave. D1[l,r] = rowsumA(i(l,r)), D2[l,r] = colsumB(j(l,r))
__global__ void probe_mfma(double* __restrict__ probe)
{
    int l = threadIdx.x;
    vdbl4 z = {0.0, 0.0, 0.0, 0.0};
    vdbl4 r1 = __builtin_amdgcn_mfma_f64_16x16x4f64((double)l, 1.0, z, 0, 0, 0);
    vdbl4 r2 = __builtin_amdgcn_mfma_f64_16x16x4f64(1.0, (double)l, z, 0, 0, 0);
#pragma unroll
    for (int r = 0; r < 4; ++r) {
        probe[r * 64 + l]       = r1[r];
        probe[256 + r * 64 + l] = r2[r];
    }
}

__global__ void decode_probe(const double* __restrict__ probe, int* __restrict__ tabs)
{
    int t = threadIdx.x;                 // 0..255
    const double* d1 = probe;
    const double* d2 = probe + 256;
    // lane=i+16k => rowsum=96+4i (mod4==0); lane=4i+k => 6+16i (mod4==2)
    bool fA = ((((int)d1[0]) & 3) == 0);
    bool fB = ((((int)d2[0]) & 3) == 0);
    int v1 = (int)d1[t], v2 = (int)d2[t];
    tabs[T_DI + t] = fA ? (v1 - 96) >> 2 : (v1 - 6) >> 4;
    tabs[T_DJ + t] = fB ? (v2 - 96) >> 2 : (v2 - 6) >> 4;
    if (t < 64) {
        tabs[T_AI + t] = fA ? (t & 15) : (t >> 2);
        tabs[T_AK + t] = fA ? (t >> 4) : (t & 3);
        tabs[T_BK + t] = fB ? (t >> 4) : (t & 3);
        tabs[T_BJ + t] = fB ? (t & 15) : (t >> 2);
    }
}

// ---------------------------------------------------------------------------
// z (8,3,64,64) fp32 -> zp (8,3,66,66) fp64 interior (borders pre-zeroed)
__global__ void prep_zpad(const float* __restrict__ z, double* __restrict__ zp)
{
    int i = blockIdx.x * blockDim.x + threadIdx.x;
    if (i >= NB * 3 * SP) return;
    int bc = i >> 12, p = i & 4095, y = p >> 6, x = p & 63;
    zp[(size_t)(bc * PS + y + 1) * PS + x + 1] = (double)z[i];
}

// conv weights OIHW fp32 -> MFMA A-fragment order (table-driven), fp64
__global__ void prep_convw_frag(const float* __restrict__ src, double* __restrict__ dst,
                                const int* __restrict__ tabs,
                                int CIN, int nlayer, int wstride)
{
    int i = blockIdx.x * blockDim.x + threadIdx.x;
    int M = CIN * 768;                   // CIN*3*4*64 per layer
    if (i >= nlayer * M) return;
    int li  = i / M;
    int rem = i - li * M;
    int t4  = rem >> 8;
    int j   = rem & 255;
    int mt  = j >> 6;
    int l   = j & 63;
    int c   = t4 / 3;
    int ph  = t4 - c * 3;
    int oc  = mt * 16 + tabs[T_AI + l];
    int tap = ph * 4 + tabs[T_AK + l];
    dst[i] = (tap < 9) ? (double)src[li * wstride + (oc * CIN + c) * 9 + tap] : 0.0;
}

// bias fp32 -> C-fragment order fp64
__global__ void prep_bias_frag(const float* __restrict__ src, double* __restrict__ dst,
                               const int* __restrict__ tabs, int nlayer)
{
    int i = blockIdx.x * blockDim.x + threadIdx.x;
    if (i >= nlayer * 1024) return;
    int li  = i >> 10;
    int j   = i & 1023;
    int mtr = j >> 6;
    int l   = j & 63;
    int mt  = mtr >> 2, r = mtr & 3;
    dst[i] = (double)src[li * 64 + mt * 16 + tabs[T_DI + r * 64 + l]];
}

// last_w (441,64) -> A-fragment order WtA[kk][mt][lane] =
// W[tap = mt*16+Ai(l)][c = kk*4+Ak(l)] (tap>=441 -> 0); lbp padded bias.
__global__ void prep_lastwa(const float* __restrict__ lw, const float* __restrict__ lb,
                            const int* __restrict__ tabs,
                            double* __restrict__ wta, double* __restrict__ lbp)
{
    int i = blockIdx.x * blockDim.x + threadIdx.x;
    if (i < WTA_N) {
        int kk = i / (28 * 64);
        int rem = i - kk * (28 * 64);
        int mt = rem >> 6;
        int l  = rem & 63;
        int c  = kk * 4 + tabs[T_AK + l];
        int T  = mt * 16 + tabs[T_AI + l];
        wta[i] = (T < K2) ? (double)lw[T * 64 + c] : 0.0;
    }
    if (i < K2P) lbp[i] = (i < K2) ? (double)lb[i] : 0.0;
}

// wsum[c] = sum_T lw[T][c] (fp64, T-ascending); wsum[64] = sum_T lb[T]
__global__ void prep_wsum(const float* __restrict__ lw, const float* __restrict__ lb,
                          double* __restrict__ wsum)
{
    int c = threadIdx.x;
    if (c < 64) {
        double s = 0.0;
        for (int t = 0; t < K2; ++t) s += (double)lw[t * 64 + c];
        wsum[c] = s;
    }
    if (c == 64) {
        double s = 0.0;
        for (int t = 0; t < K2; ++t) s += (double)lb[t];
        wsum[64] = s;
    }
}

// ---------------------------------------------------------------------------
// conv3x3 as fp64 MFMA GEMM: D(64oc x 64pos) = WF(64 x CIN*12) * P + bias.
// Depth-2 register prefetch: slot = step%3 (phase-aligned). Grid 512, 2/CU.
// ---------------------------------------------------------------------------
template<int CIN, bool RELU, bool RESADD>
__global__ __launch_bounds__(256, 2)
void conv3x3_mfma(const double* __restrict__ in, const double* __restrict__ WF,
                  const double* __restrict__ BF, const int* __restrict__ tabs,
                  const double* __restrict__ res, double* __restrict__ out)
{
    const int bid = blockIdx.x;
    const int b   = bid & 7;
    const int y0  = bid >> 3;          // output row 0..63
    const int tid = threadIdx.x;
    const int w   = tid >> 6;
    const int l   = tid & 63;
    const int mi  = w >> 1, ni = w & 1;
    const int mt0 = mi * 2, nt0 = ni * 2;

    const int kB = tabs[T_BK + l];
    const int jB = tabs[T_BJ + l];

    // per-lane P offsets for the 3 tap-phases (pad taps alias tap 8)
    int offp[3];
#pragma unroll
    for (int ph = 0; ph < 3; ++ph) {
        int tap = ph * 4 + kB;
        if (tap > 8) tap = 8;          // weight is 0 there; just needs a valid addr
        int dy = tap / 3, dx = tap - dy * 3;
        offp[ph] = dy * PS + dx + jB;
    }

    const double* bbase = in + (size_t)b * CIN * PS2 + (size_t)y0 * PS;

    vdbl4 acc[2][2];
#pragma unroll
    for (int mt = 0; mt < 2; ++mt)
#pragma unroll
        for (int r = 0; r < 4; ++r) {
            double bv = BF[((mt0 + mt) * 4 + r) * 64 + l];
            acc[mt][0][r] = bv;
            acc[mt][1][r] = bv;
        }

    double aS[3][2], bS[3][2];
    auto ldA = [&](int s, int slot) {
        const double* p = WF + (size_t)s * 256 + l;
        aS[slot][0] = p[mt0 * 64];
        aS[slot][1] = p[(mt0 + 1) * 64];
    };
    auto ldB = [&](int c, int ph, int slot) {
        const double* p = bbase + (size_t)c * PS2 + offp[ph] + nt0 * 16;
        bS[slot][0] = p[0];
        bS[slot][1] = p[16];
    };
    auto step = [&](int slot) {
        acc[0][0] = __builtin_amdgcn_mfma_f64_16x16x4f64(aS[slot][0], bS[slot][0], acc[0][0], 0, 0, 0);
        acc[0][1] = __builtin_amdgcn_mfma_f64_16x16x4f64(aS[slot][0], bS[slot][1], acc[0][1], 0, 0, 0);
        acc[1][0] = __builtin_amdgcn_mfma_f64_16x16x4f64(aS[slot][1], bS[slot][0], acc[1][0], 0, 0, 0);
        acc[1][1] = __builtin_amdgcn_mfma_f64_16x16x4f64(aS[slot][1], bS[slot][1], acc[1][1], 0, 0, 0);
    };

    // preload steps 0 and 1
    ldA(0, 0); ldB(0, 0, 0);
    ldA(1, 1); ldB(0, 1, 1);

    for (int c = 0; c < CIN; ++c) {
        const int s = 3 * c;
        ldA(s + 2, 2); ldB(c, 2, 2);
        step(0);
        if (c + 1 < CIN) { ldA(s + 3, 0); ldB(c + 1, 0, 0); }
        step(1);
        if (c + 1 < CIN) { ldA(s + 4, 1); ldB(c + 1, 1, 1); }
        step(2);
    }

    // epilogue: D element (i,j) per (lane, reg) from probe tables
    int iD[4], jD[4];
#pragma unroll
    for (int r = 0; r < 4; ++r) {
        iD[r] = tabs[T_DI + r * 64 + l];
        jD[r] = tabs[T_DJ + r * 64 + l];
    }
#pragma unroll
    for (int mt = 0; mt < 2; ++mt)
#pragma unroll
        for (int nt = 0; nt < 2; ++nt)
#pragma unroll
            for (int r = 0; r < 4; ++r) {
                int oc = (mt0 + mt) * 16 + iD[r];
                int x  = (nt0 + nt) * 16 + jD[r];
                size_t idx = (size_t)(b * NF + oc) * PS2 + (size_t)(y0 + 1) * PS + x + 1;
                double val = acc[mt][nt][r];
                if (RELU)   val = fmax(val, 0.0);
                if (RESADD) val += res[idx];
                out[idx] = val;
            }
}

// ---------------------------------------------------------------------------
// 1x1 conv as fp64 MFMA GEMM, taps-as-M: D(448taps x 64pos) = Wt * H.
// Block = (b,row), 4 waves; wave w owns mt tiles w*7..w*7+6 (tap rows),
// loops nt over the 4 pos-tiles. A = WtA fragments (L2-resident, 512B
// coalesced); B = H (coalesced 16-consecutive-pos per quad). Stores: a
// quad's 16 lanes share tap row T -> 64B contiguous float runs.
// Grid: 8 b * 64 rows = 512 blocks, 2/CU. No LDS.
// ---------------------------------------------------------------------------
__global__ __launch_bounds__(256, 2)
void lastconv_mfma(const double* __restrict__ hp, const double* __restrict__ wta,
                   const double* __restrict__ lbp, const int* __restrict__ tabs,
                   float* __restrict__ kraw)
{
    const int b   = blockIdx.x >> 6;
    const int row = blockIdx.x & 63;
    const int tid = threadIdx.x;
    const int w   = tid >> 6;
    const int l   = tid & 63;

    const int kB = tabs[T_BK + l];
    const int jB = tabs[T_BJ + l];
    int iD[4], jD[4];
#pragma unroll
    for (int r = 0; r < 4; ++r) {
        iD[r] = tabs[T_DI + r * 64 + l];
        jD[r] = tabs[T_DJ + r * 64 + l];
    }

    const double* hbase = hp + (size_t)b * NF * PS2 + (size_t)(row + 1) * PS + 1;
    float* kbase = kraw + (size_t)b * K2 * SP + row * 64;
    const int mt0 = w * 7;

    for (int nt = 0; nt < 4; ++nt) {
        vdbl4 acc[7];
#pragma unroll
        for (int n = 0; n < 7; ++n)
#pragma unroll
            for (int r = 0; r < 4; ++r)
                acc[n][r] = lbp[(mt0 + n) * 16 + iD[r]];

        // prefetch B for kk=0 (c = kB)
        double bv = hbase[(size_t)kB * PS2 + nt * 16 + jB];
        for (int kk = 0; kk < 16; ++kk) {
            double nb = 0.0;
            if (kk < 15)
                nb = hbase[(size_t)((kk + 1) * 4 + kB) * PS2 + nt * 16 + jB];
            const double* ap = wta + ((size_t)kk * 28 + mt0) * 64 + l;
#pragma unroll
            for (int n = 0; n < 7; ++n)
                acc[n] = __builtin_amdgcn_mfma_f64_16x16x4f64(ap[n * 64], bv, acc[n], 0, 0, 0);
            bv = nb;
        }

#pragma unroll
        for (int n = 0; n < 7; ++n)
#pragma unroll
            for (int r = 0; r < 4; ++r) {
                int T = (mt0 + n) * 16 + iD[r];
                if (T < K2)
                    kbase[(size_t)T * SP + nt * 16 + jD[r]] = (float)acc[n][r];
            }
    }
}

// ---------------------------------------------------------------------------
// sums[b][p] = sum_c hp[c,p] * wsum[c] + wsum[64]  (exact refactoring of the
// tap-sum; fp64 reassociation ~1e-15 rel, harmless vs 1/s amplification)
// ---------------------------------------------------------------------------
__global__ __launch_bounds__(256)
void sums_kernel(const double* __restrict__ hp, const double* __restrict__ wsum,
                 double* __restrict__ sums)
{
    int i = blockIdx.x * 256 + threadIdx.x;   // 0..32767
    int b = i >> 12, p = i & 4095;
    int y = p >> 6, x = p & 63;
    const double* hb = hp + (size_t)b * NF * PS2 + (size_t)(y + 1) * PS + 1 + x;
    double s = wsum[64];
    for (int c = 0; c < 64; ++c) s += hb[(size_t)c * PS2] * wsum[c];
    sums[b * SP + p] = s;
}

// ---------------------------------------------------------------------------
// Normalize kernel in place + apply to reflect-padded 21x21 patches of x.
// (numerics here are not 1/s-amplified, fp32 ok)
// ---------------------------------------------------------------------------
__global__ __launch_bounds__(256)
void apply_kernel(const float* __restrict__ x, const double* __restrict__ sums,
                  float* __restrict__ kout, float* __restrict__ out)
{
    const int bid  = blockIdx.x;
    const int g    = bid & 3;
    const int tile = (bid >> 2) & 15;
    const int b    = bid >> 6;
    const int i0   = (tile >> 2) << 4;
    const int j0   = (tile & 3) << 4;
    const int tid  = threadIdx.x;
    const int ti   = tid >> 4, tj = tid & 15;

    __shared__ float s_x[3][81][84];

    for (int e = tid; e < 3 * 81 * 84; e += 256) {
        int c   = e / 6804;
        int rem = e - c * 6804;
        int u   = rem / 84;
        int v   = rem - u * 84;
        int gr  = i0 * 4 + u - 10;
        int gc  = j0 * 4 + v - 10;
        gr = gr < 0 ? -gr : (gr > 255 ? 510 - gr : gr);
        gc = gc < 0 ? -gc : (gc > 255 ? 510 - gc : gc);
        int vp = (v & 3) * 21 + (v >> 2);
        s_x[c][u][vp] = x[((b * 3 + c) * 256 + gr) * 256 + gc];
    }
    __syncthreads();

    const int p = (i0 + ti) * 64 + (j0 + tj);
    const double inv = 1.0 / (sums[b * SP + p] + 1e-8);

    float o0 = 0.f, o1 = 0.f, o2 = 0.f;
    const int t0 = g * 111;
    const int t1 = (t0 + 111 < K2) ? t0 + 111 : K2;
    for (int t = t0; t < t1; ++t) {
        int ty = t / 21, tx = t - ty * 21;
        float* kp = &kout[(size_t)(b * K2 + t) * SP + p];
        float k  = *kp;
        float kn = (float)((double)k * inv);
        *kp = kn;
        int u  = ti * 4 + ty;
        int vp = (tx & 3) * 21 + tj + (tx >> 2);
        o0 = fmaf(s_x[0][u][vp], kn, o0);
        o1 = fmaf(s_x[1][u][vp], kn, o1);
        o2 = fmaf(s_x[2][u][vp], kn, o2);
    }
    atomicAdd(&out[(b * 3 + 0) * SP + p], o0);
    atomicAdd(&out[(b * 3 + 1) * SP + p], o1);
    atomicAdd(&out[(b * 3 + 2) * SP + p], o2);
}

// ---------------------------------------------------------------------------
extern "C" void kernel_launch(void* const* d_in, const int* in_sizes, int n_in,
                              void* d_out, int out_size, void* d_ws, size_t ws_size,
                              hipStream_t stream)
{
    (void)in_sizes; (void)n_in; (void)out_size; (void)ws_size;

    const float* x = (const float*)d_in[0];
    const float* z = (const float*)d_in[1];

    float* out  = (float*)d_out;                 // (8,3,64,64)
    float* kout = (float*)d_out + NB * 3 * SP;   // (8,441,64,64) raw -> normalized

    // ws layout (doubles)
    double* wd    = (double*)d_ws;
    double* probe = wd;                      // 512 (D1, D2)
    int*    tabs  = (int*)(wd + 512);        // 1024 ints (=512 doubles)
    double* wf0   = wd + 1024;               // 2304
    double* wf1   = wf0 + WF_C0;             // 8*49152
    double* wf2   = wf1 + 8 * WF_RES;        // 8*49152
    double* bf0   = wf2 + 8 * WF_RES;        // 1024
    double* bf1   = bf0 + 1024;              // 8*1024
    double* bf2   = bf1 + 8 * 1024;          // 8*1024
    double* wta   = bf2 + 8 * 1024;          // 28672
    double* lbp   = wta + WTA_N;             // 448
    double* wsum  = lbp + K2P;               // 72
    double* zp    = wsum + 72;               // 8*3*66*66
    double* hp    = zp + NB * 3 * PS2;       // 8*64*66*66 = 17.8 MB
    double* tp    = hp + NB * NF * PS2;      // 17.8 MB
    double* sums  = tp;                      // aliases tp (free after conv chain)

    // zero padded buffers (borders must be 0; interiors get overwritten)
    hipMemsetAsync(zp, 0, (size_t)NB * 3 * PS2 * sizeof(double), stream);
    hipMemsetAsync(hp, 0, (size_t)NB * NF * PS2 * sizeof(double), stream);
    hipMemsetAsync(tp, 0, (size_t)NB * NF * PS2 * sizeof(double), stream);
    hipMemsetAsync(out, 0, NB * 3 * SP * sizeof(float), stream);

    // layout probe, then table-driven prep
    probe_mfma<<<1, 64, 0, stream>>>(probe);
    decode_probe<<<1, 256, 0, stream>>>(probe, tabs);

    prep_zpad<<<(NB * 3 * SP + 255) / 256, 256, 0, stream>>>(z, zp);
    prep_convw_frag<<<(WF_C0 + 255) / 256, 256, 0, stream>>>(
        (const float*)d_in[2], wf0, tabs, 3, 1, 0);
    prep_convw_frag<<<(8 * WF_RES + 255) / 256, 256, 0, stream>>>(
        (const float*)d_in[4], wf1, tabs, 64, 8, RES_WSTRIDE);
    prep_convw_frag<<<(8 * WF_RES + 255) / 256, 256, 0, stream>>>(
        (const float*)d_in[6], wf2, tabs, 64, 8, RES_WSTRIDE);
    prep_bias_frag<<<(1024 + 255) / 256, 256, 0, stream>>>(
        (const float*)d_in[3], bf0, tabs, 1);
    prep_bias_frag<<<(8 * 1024 + 255) / 256, 256, 0, stream>>>(
        (const float*)d_in[5], bf1, tabs, 8);
    prep_bias_frag<<<(8 * 1024 + 255) / 256, 256, 0, stream>>>(
        (const float*)d_in[7], bf2, tabs, 8);
    prep_lastwa<<<(WTA_N + 255) / 256, 256, 0, stream>>>(
        (const float*)d_in[8], (const float*)d_in[9], tabs, wta, lbp);
    prep_wsum<<<1, 128, 0, stream>>>(
        (const float*)d_in[8], (const float*)d_in[9], wsum);

    conv3x3_mfma<3,  false, false><<<512, 256, 0, stream>>>(zp, wf0, bf0, tabs, nullptr, hp);
    for (int i = 0; i < 8; ++i) {
        conv3x3_mfma<64, true,  false><<<512, 256, 0, stream>>>(
            hp, wf1 + i * WF_RES, bf1 + i * 1024, tabs, nullptr, tp);
        conv3x3_mfma<64, false, true ><<<512, 256, 0, stream>>>(
            tp, wf2 + i * WF_RES, bf2 + i * 1024, tabs, hp, hp);
    }
    sums_kernel<<<128, 256, 0, stream>>>(hp, wsum, sums);
    lastconv_mfma<<<512, 256, 0, stream>>>(hp, wta, lbp, tabs, kout);
    apply_kernel<<<512, 256, 0, stream>>>(x, sums, kout, out);
}